// Round 19
// baseline (66.342 us; speedup 1.0000x reference)
//
#include <hip/hip_runtime.h>
#include <hip/hip_bf16.h>

typedef _Float16 half8 __attribute__((ext_vector_type(8)));
typedef float    floatx4 __attribute__((ext_vector_type(4)));
typedef float    floatx16 __attribute__((ext_vector_type(16)));

#define WSCALE      4096.0f
#define WSCALE_INV  (1.0f/(4096.0f*4096.0f))

#define WF16_OFF 8192   // _Float16 offset into ws; 16B-aligned

// ---- Merged prep (validated R13-R18): 256 blocks x 256 threads; each block
// redundantly computes S0..S3 -> T1,U in LDS, then its 256-elem W slice.
// ONLY CHANGE vs R13: final fragment-major mapping is for the 32x32x16 shape.
__global__ __launch_bounds__(256)
void mpo_prep(const float* __restrict__ w, _Float16* __restrict__ Wf) {
    __shared__ __align__(16) float wL[6272];
    __shared__ __align__(16) float sL[8704];   // S0@0 S1@256 S2@4352 S3@8448
    __shared__ __align__(16) float tuL[8192];  // T1@0 U@4096
    const int tid = threadIdx.x;

    {
        const floatx4* s4 = reinterpret_cast<const floatx4*>(w);
        floatx4* d4 = reinterpret_cast<floatx4*>(wL);
        for (int i = tid; i < 1568; i += 256) d4[i] = s4[i];
    }
    __syncthreads();

    // S0 (cores 0x1 @0,64)
    {
        int li = tid;
        int mm = li & 3, kk = (li >> 2) & 3, c = li >> 4;
        int k1 = kk >> 1, k2 = kk & 1, m1 = mm >> 1, m2 = mm & 1;
        float s = 0.f;
#pragma unroll
        for (int b = 0; b < 16; ++b)
            s += wL[b * 4 + k1 * 2 + m1] * wL[64 + b * 64 + c * 4 + k2 * 2 + m2];
        sL[li] = s;
    }
    // S1 tiled (cores 2x3 @1088,2112)
    {
        const int i0 = (tid >> 4) * 4, j0 = (tid & 15) * 4;
        const float* Ab = wL + 1088 + (i0 >> 2) * 64;
        const float* Bb = wL + 2112 + j0;
        float acc[4][4] = {};
#pragma unroll
        for (int b = 0; b < 16; ++b) {
            floatx4 ar = *reinterpret_cast<const floatx4*>(Ab + b * 4);
            floatx4 br = *reinterpret_cast<const floatx4*>(Bb + b * 64);
#pragma unroll
            for (int r = 0; r < 4; ++r)
#pragma unroll
                for (int s = 0; s < 4; ++s) acc[r][s] += ar[r] * br[s];
        }
#pragma unroll
        for (int r = 0; r < 4; ++r)
#pragma unroll
        for (int s = 0; s < 4; ++s) {
            int i = i0 + r, j = j0 + s;
            sL[256 + (i >> 2) * 256 + (j >> 2) * 16 +
               ((i >> 1) & 1) * 8 + ((j >> 1) & 1) * 4 + (i & 1) * 2 + (j & 1)] = acc[r][s];
        }
    }
    // S2 tiled (cores 4x5 @3136,4160)
    {
        const int i0 = (tid >> 4) * 4, j0 = (tid & 15) * 4;
        const float* Ab = wL + 3136 + (i0 >> 2) * 64;
        const float* Bb = wL + 4160 + j0;
        float acc[4][4] = {};
#pragma unroll
        for (int b = 0; b < 16; ++b) {
            floatx4 ar = *reinterpret_cast<const floatx4*>(Ab + b * 4);
            floatx4 br = *reinterpret_cast<const floatx4*>(Bb + b * 64);
#pragma unroll
            for (int r = 0; r < 4; ++r)
#pragma unroll
                for (int s = 0; s < 4; ++s) acc[r][s] += ar[r] * br[s];
        }
#pragma unroll
        for (int r = 0; r < 4; ++r)
#pragma unroll
        for (int s = 0; s < 4; ++s) {
            int i = i0 + r, j = j0 + s;
            sL[4352 + (i >> 2) * 256 + (j >> 2) * 16 +
               ((i >> 1) & 1) * 8 + ((j >> 1) & 1) * 4 + (i & 1) * 2 + (j & 1)] = acc[r][s];
        }
    }
    // S3 (cores 6x7 @5184,6208)
    {
        int li = tid;
        int mm = li & 3, kk = (li >> 2) & 3, a = li >> 4;
        int k1 = kk >> 1, k2 = kk & 1, m1 = mm >> 1, m2 = mm & 1;
        float s = 0.f;
#pragma unroll
        for (int b = 0; b < 16; ++b)
            s += wL[5184 + a * 64 + b * 4 + k1 * 2 + m1] * wL[6208 + b * 4 + k2 * 2 + m2];
        sL[8448 + li] = s;
    }
    __syncthreads();

    // T1 tiled -> tuL[0:4096)
    {
        const int p0 = (tid >> 6) * 4, q0 = (tid & 63) * 4;
        float acc[4][4] = {};
#pragma unroll
        for (int a = 0; a < 16; ++a) {
            floatx4 pr = *reinterpret_cast<const floatx4*>(sL + a * 16 + p0);
            floatx4 qr = *reinterpret_cast<const floatx4*>(sL + 256 + a * 256 + q0);
#pragma unroll
            for (int r = 0; r < 4; ++r)
#pragma unroll
                for (int s = 0; s < 4; ++s) acc[r][s] += pr[r] * qr[s];
        }
#pragma unroll
        for (int r = 0; r < 4; ++r)
#pragma unroll
        for (int s = 0; s < 4; ++s) {
            int p = p0 + r, q = q0 + s;
            tuL[(q >> 4) * 256 + ((p >> 2) * 4 + ((q >> 2) & 3)) * 16 +
                (p & 3) * 4 + (q & 3)] = acc[r][s];
        }
    }
    // U tiled -> tuL[4096:8192)
    {
        const int r0 = (tid >> 2) * 4, q0 = (tid & 3) * 4;
        float acc[4][4] = {};
#pragma unroll
        for (int b = 0; b < 16; ++b) {
            floatx4 ar = *reinterpret_cast<const floatx4*>(sL + 4352 + (r0 >> 4) * 256 + b * 16 + (r0 & 15));
            floatx4 br = *reinterpret_cast<const floatx4*>(sL + 8448 + b * 16 + q0);
#pragma unroll
            for (int r = 0; r < 4; ++r)
#pragma unroll
                for (int s = 0; s < 4; ++s) acc[r][s] += ar[r] * br[s];
        }
#pragma unroll
        for (int r = 0; r < 4; ++r)
#pragma unroll
        for (int s = 0; s < 4; ++s)
            tuL[4096 + (r0 + r) * 16 + q0 + s] = acc[r][s];
    }
    __syncthreads();

    // W slice, 32x32x16 fragment-major:
    // strip n=col>>5 (32 cols), cc=col&31, k-chunk kq=k>>4, hh=(k>>3)&1, jj=k&7
    // lane = hh*32+cc supplies B[k=kq*16+hh*8+jj][col] -> half8 idx (n*16+kq)*64+lane
    {
        int idx = blockIdx.x * 256 + tid;
        int J4 = idx & 255, I4 = idx >> 8;
        int I16 = I4 >> 4, kc = (I4 >> 2) & 3, k2v = I4 & 3;
        int mc = (J4 >> 2) & 3, m2v = J4 & 3;
        int J16 = J4 >> 4;
        const float* Uc = tuL + 4096 + (((kc * 4 + mc) * 4 + k2v) * 4 + m2v);
        float s = 0.f;
#pragma unroll
        for (int a = 0; a < 16; ++a)
            s += tuL[(a * 16 + I16) * 16 + J16] * Uc[a * 256];
        int nn = J4 >> 5, cc = J4 & 31, kq = I4 >> 4, hh = (I4 >> 3) & 1, jj = I4 & 7;
        Wf[(((nn * 16 + kq) * 64) + hh * 32 + cc) * 8 + jj] = (_Float16)(s * WSCALE);
    }
}

// ---- Main fused kernel: R13 pipeline rhythm + 32x32x16 MFMA ----
// 256 blocks x 512 threads (8 waves, 2/SIMD), W (128 KB) + dk in LDS, one
// barrier. Each wave owns 32 rows/set (lane&31 = its row), 4 sets of 256
// block-rows. DS B-reads HALVED vs R13 (128 b128 per 32 rows): DS/CU/set
// ~16K cyc << HBM 25.6K -> HBM-paced. Half-set (kk 0-7 / 8-15) single-buffer
// rotation: nloop hides under half0(s+1) delivery; cvt-half1 wait hides
// under half1 delivery; HBM continuous by construction. ~193 VGPR.
__global__ __launch_bounds__(512, 2)
void mpo_main(const float* __restrict__ x, const _Float16* __restrict__ Wf,
              const float* __restrict__ dk, const float* __restrict__ bias,
              float* __restrict__ out) {
    extern __shared__ _Float16 Wl[];                       // 65536 halves + 256 floats
    float* dkL = reinterpret_cast<float*>(Wl + 65536);

    const int tid  = threadIdx.x;
    const int lane = tid & 63;
    const int wave = tid >> 6;        // 0..7
    const int col  = lane & 31;       // A row selector AND D col selector
    const int hi   = lane >> 5;       // k-subchunk selector

    const long blockbase = (long)blockIdx.x * 1024;
    // wave's row (this lane): set s -> blockbase + s*256 + wave*32 + col
    const float* xr = x + (blockbase + wave * 32 + col) * 256 + hi * 8;
    const int SS = 256 * 256;         // floats per set (256 rows)

    half8 a[16];
    floatx4 lob[8], hib[8];

#define SB()  __builtin_amdgcn_sched_barrier(0)
// load half h (kk = h*8 .. h*8+7) of set s into the buffer
#define XLDH(s, h) do { _Pragma("unroll")                                \
    for (int i_ = 0; i_ < 8; ++i_) {                                     \
        const float* p_ = xr + (s) * SS + ((h) * 8 + i_) * 16;           \
        lob[i_] = *reinterpret_cast<const floatx4*>(p_);                 \
        hib[i_] = *reinterpret_cast<const floatx4*>(p_ + 4);             \
    } } while (0)
// convert buffer into a[h*8 .. h*8+7]
#define XCVTH(h) do { _Pragma("unroll")                                  \
    for (int i_ = 0; i_ < 8; ++i_) {                                     \
        half8 f_;                                                        \
        f_[0] = (_Float16)lob[i_][0]; f_[1] = (_Float16)lob[i_][1];      \
        f_[2] = (_Float16)lob[i_][2]; f_[3] = (_Float16)lob[i_][3];      \
        f_[4] = (_Float16)hib[i_][0]; f_[5] = (_Float16)hib[i_][1];      \
        f_[6] = (_Float16)hib[i_][2]; f_[7] = (_Float16)hib[i_][3];      \
        a[(h) * 8 + i_] = f_;                                            \
    } } while (0)

    // ---- prologue ----
    XLDH(0, 0);
    SB();
    {
        const floatx4* src = reinterpret_cast<const floatx4*>(Wf);
        floatx4* dst = reinterpret_cast<floatx4*>(Wl);
#pragma unroll
        for (int i = 0; i < 16; ++i)
            dst[tid + i * 512] = src[tid + i * 512];
    }
    if (tid < 256) dkL[tid] = dk[tid];
    const float bs = bias[0];
    __syncthreads();   // the only barrier

    float kreg[8];
#pragma unroll
    for (int n = 0; n < 8; ++n) kreg[n] = dkL[n * 32 + col];

    XCVTH(0);          // waits half0(set0)
    XLDH(0, 1);        // issue half1(set0)
    SB();
    XCVTH(1);          // waits half1(set0)
    XLDH(1, 0);        // issue half0(set1)
    SB();

    const half8* Wv = reinterpret_cast<const half8*>(Wl);

#pragma unroll 1
    for (int s = 0; s < 4; ++s) {
        floatx16 rp = {0,0,0,0,0,0,0,0,0,0,0,0,0,0,0,0};
#pragma unroll 1
        for (int n = 0; n < 8; ++n) {
            const half8* Wn = Wv + n * 1024 + lane;
            floatx16 c = {0,0,0,0,0,0,0,0,0,0,0,0,0,0,0,0};
#pragma unroll
            for (int kk = 0; kk < 16; ++kk)
                c = __builtin_amdgcn_mfma_f32_32x32x16_f16(a[kk], Wn[kk * 64], c, 0, 0, 0);
            const float kv = kreg[n];
#pragma unroll
            for (int r = 0; r < 16; ++r) rp[r] += c[r] * c[r] * kv;
        }

        // rotate: a[0..7] <- half0(s+1) (aged ~1 full set: no stall); issue half1(s+1)
        if (s < 3) { XCVTH(0); XLDH(s + 1, 1); }
        SB();

        // reduce over the 32 cols (5 xor steps within each half-wave); store
#pragma unroll
        for (int r = 0; r < 16; ++r) {
            float v = rp[r];
            v += __shfl_xor(v, 1);
            v += __shfl_xor(v, 2);
            v += __shfl_xor(v, 4);
            v += __shfl_xor(v, 8);
            v += __shfl_xor(v, 16);
            rp[r] = v;
        }
        if (col == 0) {
            float* ob = out + blockbase + s * 256 + wave * 32 + hi * 4;
#pragma unroll
            for (int r = 0; r < 16; ++r)
                ob[(r & 3) + 8 * (r >> 2)] = rp[r] * WSCALE_INV + bs;
        }

        // a[8..15] <- half1(s+1) (wait hides under its HBM delivery); issue half0(s+2)
        if (s < 3) { XCVTH(1); }
        if (s < 2) { XLDH(s + 2, 0); }
        SB();
    }
}

extern "C" void kernel_launch(void* const* d_in, const int* in_sizes, int n_in,
                              void* d_out, int out_size, void* d_ws, size_t ws_size,
                              hipStream_t stream) {
    const float* x    = (const float*)d_in[0];
    const float* w    = (const float*)d_in[1];
    const float* dk   = (const float*)d_in[2];
    const float* bias = (const float*)d_in[3];
    float* out = (float*)d_out;
    float* ws  = (float*)d_ws;

    _Float16* Wf16 = (_Float16*)(ws + WF16_OFF);

    // Allow 129 KB dynamic LDS for mpo_main (host-side attr; validated R5-R18).
    static bool attr_set = false;
    if (!attr_set) {
        hipFuncSetAttribute((const void*)mpo_main,
                            hipFuncAttributeMaxDynamicSharedMemorySize, 132096);
        attr_set = true;
    }

    // W contraction: ONE kernel (per-block redundant T1/U + W slice)
    mpo_prep<<<256, 256, 0, stream>>>(w, Wf16);

    // Main fused GEMM + square + dot: 256 blocks x 512 threads, 129 KB LDS
    mpo_main<<<256, 512, 132096, stream>>>(x, Wf16, dk, bias, out);
}

// Round 20
// 62.178 us; speedup vs baseline: 1.0670x; 1.0670x over previous
//
#include <hip/hip_runtime.h>
#include <hip/hip_bf16.h>

typedef _Float16 half8 __attribute__((ext_vector_type(8)));
typedef float    floatx4 __attribute__((ext_vector_type(4)));

#define WSCALE      4096.0f
#define WSCALE_INV  (1.0f/(4096.0f*4096.0f))

#define WF16_OFF 8192   // _Float16 offset into ws (floats 0..8191 spare); 16B-aligned

// ---- Merged prep: ONE kernel, 256 blocks x 256 threads. Each block
// redundantly computes S0..S3 -> T1,U in LDS (validated tiled code, ~1 us,
// fully parallel across CUs), then its 256-element fragment-major W slice.
__global__ __launch_bounds__(256)
void mpo_prep(const float* __restrict__ w, _Float16* __restrict__ Wf) {
    __shared__ __align__(16) float wL[6272];
    __shared__ __align__(16) float sL[8704];   // S0@0 S1@256 S2@4352 S3@8448
    __shared__ __align__(16) float tuL[8192];  // T1@0 U@4096
    const int tid = threadIdx.x;

    // stage all 8 cores (6272 floats = 1568 float4)
    {
        const floatx4* s4 = reinterpret_cast<const floatx4*>(w);
        floatx4* d4 = reinterpret_cast<floatx4*>(wL);
        for (int i = tid; i < 1568; i += 256) d4[i] = s4[i];
    }
    __syncthreads();

    // S0 (cores 0x1 @0,64): scalar, 256 outs
    {
        int li = tid;
        int mm = li & 3, kk = (li >> 2) & 3, c = li >> 4;
        int k1 = kk >> 1, k2 = kk & 1, m1 = mm >> 1, m2 = mm & 1;
        float s = 0.f;
#pragma unroll
        for (int b = 0; b < 16; ++b)
            s += wL[b * 4 + k1 * 2 + m1] * wL[64 + b * 64 + c * 4 + k2 * 2 + m2];
        sL[li] = s;
    }
    // S1 tiled (cores 2x3 @1088,2112)
    {
        const int i0 = (tid >> 4) * 4, j0 = (tid & 15) * 4;
        const float* Ab = wL + 1088 + (i0 >> 2) * 64;
        const float* Bb = wL + 2112 + j0;
        float acc[4][4] = {};
#pragma unroll
        for (int b = 0; b < 16; ++b) {
            floatx4 ar = *reinterpret_cast<const floatx4*>(Ab + b * 4);
            floatx4 br = *reinterpret_cast<const floatx4*>(Bb + b * 64);
#pragma unroll
            for (int r = 0; r < 4; ++r)
#pragma unroll
                for (int s = 0; s < 4; ++s) acc[r][s] += ar[r] * br[s];
        }
#pragma unroll
        for (int r = 0; r < 4; ++r)
#pragma unroll
        for (int s = 0; s < 4; ++s) {
            int i = i0 + r, j = j0 + s;
            sL[256 + (i >> 2) * 256 + (j >> 2) * 16 +
               ((i >> 1) & 1) * 8 + ((j >> 1) & 1) * 4 + (i & 1) * 2 + (j & 1)] = acc[r][s];
        }
    }
    // S2 tiled (cores 4x5 @3136,4160)
    {
        const int i0 = (tid >> 4) * 4, j0 = (tid & 15) * 4;
        const float* Ab = wL + 3136 + (i0 >> 2) * 64;
        const float* Bb = wL + 4160 + j0;
        float acc[4][4] = {};
#pragma unroll
        for (int b = 0; b < 16; ++b) {
            floatx4 ar = *reinterpret_cast<const floatx4*>(Ab + b * 4);
            floatx4 br = *reinterpret_cast<const floatx4*>(Bb + b * 64);
#pragma unroll
            for (int r = 0; r < 4; ++r)
#pragma unroll
                for (int s = 0; s < 4; ++s) acc[r][s] += ar[r] * br[s];
        }
#pragma unroll
        for (int r = 0; r < 4; ++r)
#pragma unroll
        for (int s = 0; s < 4; ++s) {
            int i = i0 + r, j = j0 + s;
            sL[4352 + (i >> 2) * 256 + (j >> 2) * 16 +
               ((i >> 1) & 1) * 8 + ((j >> 1) & 1) * 4 + (i & 1) * 2 + (j & 1)] = acc[r][s];
        }
    }
    // S3 (cores 6x7 @5184,6208): scalar, 256 outs
    {
        int li = tid;
        int mm = li & 3, kk = (li >> 2) & 3, a = li >> 4;
        int k1 = kk >> 1, k2 = kk & 1, m1 = mm >> 1, m2 = mm & 1;
        float s = 0.f;
#pragma unroll
        for (int b = 0; b < 16; ++b)
            s += wL[5184 + a * 64 + b * 4 + k1 * 2 + m1] * wL[6208 + b * 4 + k2 * 2 + m2];
        sL[8448 + li] = s;
    }
    __syncthreads();

    // T1 tiled -> tuL[0:4096)
    {
        const int p0 = (tid >> 6) * 4, q0 = (tid & 63) * 4;
        float acc[4][4] = {};
#pragma unroll
        for (int a = 0; a < 16; ++a) {
            floatx4 pr = *reinterpret_cast<const floatx4*>(sL + a * 16 + p0);
            floatx4 qr = *reinterpret_cast<const floatx4*>(sL + 256 + a * 256 + q0);
#pragma unroll
            for (int r = 0; r < 4; ++r)
#pragma unroll
                for (int s = 0; s < 4; ++s) acc[r][s] += pr[r] * qr[s];
        }
#pragma unroll
        for (int r = 0; r < 4; ++r)
#pragma unroll
        for (int s = 0; s < 4; ++s) {
            int p = p0 + r, q = q0 + s;
            tuL[(q >> 4) * 256 + ((p >> 2) * 4 + ((q >> 2) & 3)) * 16 +
                (p & 3) * 4 + (q & 3)] = acc[r][s];
        }
    }
    // U tiled -> tuL[4096:8192)
    {
        const int r0 = (tid >> 2) * 4, q0 = (tid & 3) * 4;
        float acc[4][4] = {};
#pragma unroll
        for (int b = 0; b < 16; ++b) {
            floatx4 ar = *reinterpret_cast<const floatx4*>(sL + 4352 + (r0 >> 4) * 256 + b * 16 + (r0 & 15));
            floatx4 br = *reinterpret_cast<const floatx4*>(sL + 8448 + b * 16 + q0);
#pragma unroll
            for (int r = 0; r < 4; ++r)
#pragma unroll
                for (int s = 0; s < 4; ++s) acc[r][s] += ar[r] * br[s];
        }
#pragma unroll
        for (int r = 0; r < 4; ++r)
#pragma unroll
        for (int s = 0; s < 4; ++s)
            tuL[4096 + (r0 + r) * 16 + q0 + s] = acc[r][s];
    }
    __syncthreads();

    // W slice: this block's 256 elements (16 MACs each, LDS-hot)
    {
        int idx = blockIdx.x * 256 + tid;              // 65536 total
        int J4 = idx & 255, I4 = idx >> 8;             // col, k
        int I16 = I4 >> 4, kc = (I4 >> 2) & 3, k2v = I4 & 3;
        int mc = (J4 >> 2) & 3, m2v = J4 & 3;
        int J16 = J4 >> 4;
        const float* Uc = tuL + 4096 + (((kc * 4 + mc) * 4 + k2v) * 4 + m2v);
        float s = 0.f;
#pragma unroll
        for (int a = 0; a < 16; ++a)
            s += tuL[(a * 16 + I16) * 16 + J16] * Uc[a * 256];
        int nn = J4 >> 4, lr = J4 & 15, kq = I4 >> 5, gg = (I4 >> 3) & 3, jj = I4 & 7;
        Wf[(((nn * 8 + kq) * 64) + gg * 16 + lr) * 8 + jj] = (_Float16)(s * WSCALE);
    }
}

// ---- Main fused kernel: SINGLE-SET fine-grained pipeline (R13, best) ----
// 256 blocks x 512 threads, W (128 KB) + dk in LDS, one barrier. 8 sets of
// 16 rows/wave; per set: {cvt a <- set s; issue set s+2; nloop(a); reduce}.
// Per-set delivery (12.5K cyc) ~= per-set LDS n-loop (12.3K) -> balanced
// pipeline, no coarse fill/drain bubbles. dk in registers (kreg) keeps the
// DS pipe to B-reads only.
__global__ __launch_bounds__(512, 2)
void mpo_main(const float* __restrict__ x, const _Float16* __restrict__ Wf,
              const float* __restrict__ dk, const float* __restrict__ bias,
              float* __restrict__ out) {
    extern __shared__ _Float16 Wl[];                       // 65536 halves + 256 floats
    float* dkL = reinterpret_cast<float*>(Wl + 65536);

    const int tid  = threadIdx.x;
    const int lane = tid & 63;
    const int wave = tid >> 6;        // 0..7
    const int lrow = lane & 15;
    const int g    = lane >> 4;

    const long blockbase = (long)blockIdx.x * 1024;
    // wave's rows for set s: blockbase + s*128 + wave*16 + (g*4+r)
    const float* xb = x + (blockbase + wave * 16 + lrow) * 256 + g * 8;
    const int SET_STRIDE = 128 * 256;   // floats per set (128 rows)

    half8 a[8];
    floatx4 lo[8], hi[8];

#define SB()  __builtin_amdgcn_sched_barrier(0)
#define XLD(i, xn) do { const float* p_ = (xn) + (i) * 32;              \
                     lo[i] = *reinterpret_cast<const floatx4*>(p_);     \
                     hi[i] = *reinterpret_cast<const floatx4*>(p_ + 4); } while (0)
#define XLD_ALL(xn) do { XLD(0,xn); XLD(1,xn); XLD(2,xn); XLD(3,xn); \
                         XLD(4,xn); XLD(5,xn); XLD(6,xn); XLD(7,xn); } while (0)
#define XCVT(i) do { half8 f_;                                                \
                     f_[0] = (_Float16)lo[i][0]; f_[1] = (_Float16)lo[i][1];  \
                     f_[2] = (_Float16)lo[i][2]; f_[3] = (_Float16)lo[i][3];  \
                     f_[4] = (_Float16)hi[i][0]; f_[5] = (_Float16)hi[i][1];  \
                     f_[6] = (_Float16)hi[i][2]; f_[7] = (_Float16)hi[i][3];  \
                     a[i] = f_; } while (0)
#define XCVT_ALL() do { XCVT(0); XCVT(1); XCVT(2); XCVT(3); \
                        XCVT(4); XCVT(5); XCVT(6); XCVT(7); } while (0)

    // ---- prologue: issue set0; stage W+dk; barrier (drains set0 = fill) ----
    XLD_ALL(xb);
    SB();
    {
        const floatx4* src = reinterpret_cast<const floatx4*>(Wf);
        floatx4* dst = reinterpret_cast<floatx4*>(Wl);
#pragma unroll
        for (int i = 0; i < 16; ++i)
            dst[tid + i * 512] = src[tid + i * 512];
    }
    if (tid < 256) dkL[tid] = dk[tid];
    const float bs = bias[0];
    __syncthreads();   // the only barrier

    float kreg[16];
#pragma unroll
    for (int n = 0; n < 16; ++n) kreg[n] = dkL[n * 16 + lrow];

    XCVT_ALL();                 // a <- set 0
    XLD_ALL(xb + SET_STRIDE);   // issue set 1
    SB();

    const half8* Wv = reinterpret_cast<const half8*>(Wl);

#pragma unroll 1
    for (int s = 0; s < 8; ++s) {
        float rp[4] = {0, 0, 0, 0};
#pragma unroll 1
        for (int n = 0; n < 16; ++n) {
            const half8* Wn = Wv + n * 512 + lane;
            floatx4 c0 = {0, 0, 0, 0};
#pragma unroll
            for (int kk = 0; kk < 8; ++kk)
                c0 = __builtin_amdgcn_mfma_f32_16x16x32_f16(a[kk], Wn[kk * 64], c0, 0, 0, 0);
            const float kv = kreg[n];
#pragma unroll
            for (int r = 0; r < 4; ++r)
                rp[r] += c0[r] * c0[r] * kv;
        }

        // rotate the pipeline: a <- set s+1 (small stall), issue set s+2
        if (s < 7) { XCVT_ALL(); }
        if (s < 6) { XLD_ALL(xb + (s + 2) * SET_STRIDE); }
        SB();

        // reduce over the 16 cols (lanes sharing g) and store this set
#pragma unroll
        for (int r = 0; r < 4; ++r) {
            float v = rp[r];
            v += __shfl_xor(v, 1);
            v += __shfl_xor(v, 2);
            v += __shfl_xor(v, 4);
            v += __shfl_xor(v, 8);
            rp[r] = v;
        }
        if (lrow == 0) {
            floatx4 o;
#pragma unroll
            for (int r = 0; r < 4; ++r) o[r] = rp[r] * WSCALE_INV + bs;
            *reinterpret_cast<floatx4*>(out + blockbase + s * 128 + wave * 16 + g * 4) = o;
        }
        SB();
    }
}

extern "C" void kernel_launch(void* const* d_in, const int* in_sizes, int n_in,
                              void* d_out, int out_size, void* d_ws, size_t ws_size,
                              hipStream_t stream) {
    const float* x    = (const float*)d_in[0];
    const float* w    = (const float*)d_in[1];
    const float* dk   = (const float*)d_in[2];
    const float* bias = (const float*)d_in[3];
    float* out = (float*)d_out;
    float* ws  = (float*)d_ws;

    _Float16* Wf16 = (_Float16*)(ws + WF16_OFF);

    // Allow 129 KB dynamic LDS for mpo_main (host-side attr; validated R5-R19).
    static bool attr_set = false;
    if (!attr_set) {
        hipFuncSetAttribute((const void*)mpo_main,
                            hipFuncAttributeMaxDynamicSharedMemorySize, 132096);
        attr_set = true;
    }

    // W contraction: ONE kernel (per-block redundant T1/U + W slice)
    mpo_prep<<<256, 256, 0, stream>>>(w, Wf16);

    // Main fused GEMM + square + dot: 256 blocks x 512 threads, 129 KB LDS
    mpo_main<<<256, 512, 132096, stream>>>(x, Wf16, dk, bias, out);
}